// Round 8
// baseline (468.730 us; speedup 1.0000x reference)
//
#include <hip/hip_runtime.h>

typedef _Float16 h16;
typedef __attribute__((ext_vector_type(8))) _Float16 h16x8;
typedef __attribute__((ext_vector_type(4))) float f32x4;
typedef unsigned int u32;

#define BARRIER() __builtin_amdgcn_s_barrier()
#define SCHEDB()  __builtin_amdgcn_sched_barrier(0)
#define VMCNT_(n) asm volatile("s_waitcnt vmcnt(" #n ")" ::: "memory")
#define VMCNT(n)  VMCNT_(n)

// ---------------- Kernel 1: A fp32 -> fp16 ----------------
__global__ __launch_bounds__(256) void cvtA_kernel(const float* __restrict__ A,
                                                   h16* __restrict__ Ah, int total8) {
  int stride = gridDim.x * blockDim.x;
  for (int i = blockIdx.x * blockDim.x + threadIdx.x; i < total8; i += stride) {
    const f32x4* p = (const f32x4*)(A + (size_t)i * 8);
    f32x4 v0 = p[0], v1 = p[1];
    h16x8 o;
    o[0] = (h16)v0[0]; o[1] = (h16)v0[1]; o[2] = (h16)v0[2]; o[3] = (h16)v0[3];
    o[4] = (h16)v1[0]; o[5] = (h16)v1[1]; o[6] = (h16)v1[2]; o[7] = (h16)v1[3];
    *(h16x8*)(Ah + (size_t)i * 8) = o;
  }
}

// ---------------- Kernel 2: dequant 2:4 int4 -> Wt [N][K] fp16 ----------------
__global__ __launch_bounds__(256) void dequant_kernel(const int* __restrict__ Bq,
    const int* __restrict__ meta, const float* __restrict__ s,
    h16* __restrict__ Wt, int K, int N, int chunksPerGroup) {
  int n = blockIdx.x * 256 + threadIdx.x;
  int chunk = blockIdx.y;
  u32 w0 = (u32)Bq[(size_t)(chunk * 2) * N + n];
  u32 w1 = (u32)Bq[(size_t)(chunk * 2 + 1) * N + n];
  float sc = s[(size_t)(chunk / chunksPerGroup) * N + n];
  h16 out[32];
#pragma unroll
  for (int gi = 0; gi < 8; ++gi) {
    int g = chunk * 8 + gi;
    int mm = meta[(size_t)g * N + n];
    u32 w = (gi < 4) ? w0 : w1;
    int j0 = (2 * gi) & 7;
    float d0 = (float)((int)((w >> (4 * j0)) & 0xFu) - 8) * sc;
    float d1 = (float)((int)((w >> (4 * j0 + 4)) & 0xFu) - 8) * sc;
    u32 enc = (0xED9C84u >> (4 * mm)) & 0xFu;
    int p0 = (int)(enc & 3u), p1 = (int)(enc >> 2);
#pragma unroll
    for (int p = 0; p < 4; ++p) {
      float v = (p == p0) ? d0 : ((p == p1) ? d1 : 0.0f);
      out[gi * 4 + p] = (h16)v;
    }
  }
  h16* dst = Wt + (size_t)n * K + chunk * 32;
  *(h16x8*)(dst + 0)  = *(h16x8*)(out + 0);
  *(h16x8*)(dst + 8)  = *(h16x8*)(out + 8);
  *(h16x8*)(dst + 16) = *(h16x8*)(out + 16);
  *(h16x8*)(dst + 24) = *(h16x8*)(out + 24);
}

// ---------------- Kernel 3 helpers ----------------
__device__ __forceinline__ void rdA(h16x8 (&d)[4][2], const h16* base, int row,
                                    int s0, int s1) {
#pragma unroll
  for (int m = 0; m < 4; ++m) {
    d[m][0] = *(const h16x8*)(base + row + m * 1024 + s0);
    d[m][1] = *(const h16x8*)(base + row + m * 1024 + s1);
  }
}
__device__ __forceinline__ void loadB(h16x8 (&b)[4][2], const h16* Wb, size_t K, int T) {
#pragma unroll
  for (int n = 0; n < 4; ++n)
#pragma unroll
    for (int ks = 0; ks < 2; ++ks)
      b[n][ks] = *(const h16x8*)(Wb + (size_t)n * 16 * K + ks * 32 + (size_t)T * 64);
}
__device__ __forceinline__ void mfma32(f32x4 (&acc)[8][4], int mo,
                                       const h16x8 (&a)[4][2], const h16x8 (&b)[4][2]) {
#pragma unroll
  for (int m = 0; m < 4; ++m)
#pragma unroll
    for (int n = 0; n < 4; ++n) {
      acc[mo + m][n] = __builtin_amdgcn_mfma_f32_16x16x32_f16(a[m][0], b[n][0], acc[mo + m][n], 0, 0, 0);
      acc[mo + m][n] = __builtin_amdgcn_mfma_f32_16x16x32_f16(a[m][1], b[n][1], acc[mo + m][n], 0, 0, 0);
    }
}

// ---------------- Kernel 3: GEMM, A-in-LDS / B-direct-from-L2 ----------------
// 256x256 tile, K-tiles of 64, 512 threads (8 waves 2Mx4N), per-wave 128x64.
// LDS: A only, 4 rotating buffers x 2 halves x [128 rows x 64] = 128 KiB.
// B fragments load straight from global (Wt K-major == fragment layout);
// prefetched 1 tile ahead into bX/bY (2-tile unroll). tn-major XCD swizzle
// keeps each XCD's B-slab (2 MiB) L2-resident.
// Per tile: P1{rd A-h0 | loadB(T+1) | stage(T+2)h0 | MFMA rows 0-63 | barrier}
//           P2{rd A-h1 | stage(T+2)h1 | vmcnt(14) | barrier | MFMA rows 64-127}
// Publish chain: (T)h0 via prev-tile vmcnt(14)+barrier; (T)h1 via this tile's
// compiler-inserted B(T)-wait (B(T) issued after stg(T)h1 -> retire-through)
// + P1-end barrier. Prologue vmcnt(4); tail vmcnt(10) then none.
__global__ __launch_bounds__(512, 2) void gemm_kernel(const h16* __restrict__ A,
    const h16* __restrict__ Wt, const float* __restrict__ bias,
    float* __restrict__ C, int M, int N, int K) {
  __shared__ alignas(16) h16 As[4 * 2 * 8192];

  const size_t Kl = (size_t)K;
  const int nTilesM = M >> 8;
  const int nwg = gridDim.x;
  int bid = blockIdx.x;
  int wg = (bid & 7) * (nwg >> 3) + (bid >> 3);   // XCD swizzle (nwg%8==0)
  int tn = wg / nTilesM, tm = wg - tn * nTilesM;  // tn-major: XCD shares B-slab

  const int tid = threadIdx.x;
  const int lane = tid & 63, w = tid >> 6;
  const int wr = w >> 2, wc = w & 3;

  // ---- A staging (pre-swizzled global source, linear LDS dest) ----
  const int i0 = tid >> 3;                         // row within 64-row chunk
  const int sigma = (tid & 7) ^ ((tid >> 3) & 7);  // source 16B-slot swizzle
  const h16* gA_t = A + ((size_t)(tm * 256) + i0) * Kl + sigma * 8;
  const int tid8 = tid * 8;
  const size_t rowK128 = (size_t)128 * Kl;
  h16* AsF = As;

#define GLOAD(SRC, DST) __builtin_amdgcn_global_load_lds(                      \
    (const __attribute__((address_space(1))) void*)(SRC),                      \
    (__attribute__((address_space(3))) void*)(DST), 16, 0, 0)

#define STAGE_A(T_, h_) do {                                                   \
    const h16* s_ = gA_t + (size_t)((h_) * 64) * Kl + (size_t)(T_) * 64;       \
    h16* d_ = AsF + ((((T_) & 3) * 2 + (h_)) * 8192) + tid8;                   \
    GLOAD(s_, d_); GLOAD(s_ + rowK128, d_ + 4096); } while (0)

  // ---- fragment read offsets (swizzled slot = (ks*4+l16)^l7) ----
  const int ln15 = lane & 15, l16 = lane >> 4, l7 = lane & 7;
  const int aRow = (wr * 64 + ln15) * 64;
  const int sl0 = ((0 + l16) ^ l7) * 8;
  const int sl1 = ((4 + l16) ^ l7) * 8;

  // ---- B direct-global base: lane covers Wt row (col of C), 16B k-chunk ----
  const h16* Wb = Wt + ((size_t)(tn * 256 + wc * 64 + ln15)) * Kl + l16 * 8;

  f32x4 acc[8][4] = {};
  h16x8 af[4][2], bX[4][2], bY[4][2];
  const int NT = K >> 6;          // even, >= 4

  // prologue: B(0)->bX; stage tiles 0,1; retire through stg(0)h1.
  loadB(bX, Wb, Kl, 0);
  STAGE_A(0, 0); STAGE_A(0, 1); STAGE_A(1, 0); STAGE_A(1, 1);
  SCHEDB(); VMCNT(4); BARRIER(); SCHEDB();

#define TILE(T_, BCUR, BNXT, GB_, GS_, VM_P2) do {                             \
    const h16* aH0 = AsF + (((T_) & 3) * 2 + 0) * 8192;                        \
    const h16* aH1 = AsF + (((T_) & 3) * 2 + 1) * 8192;                        \
    /* ---- P1 ---- */                                                         \
    rdA(af, aH0, aRow, sl0, sl1);                                              \
    if (GB_) loadB(BNXT, Wb, Kl, (T_) + 1);                                    \
    if (GS_) STAGE_A((T_) + 2, 0);                                             \
    SCHEDB();                                                                  \
    __builtin_amdgcn_s_setprio(1); mfma32(acc, 0, af, BCUR);                   \
    __builtin_amdgcn_s_setprio(0);                                             \
    SCHEDB(); BARRIER(); SCHEDB();                                             \
    /* ---- P2 ---- */                                                         \
    rdA(af, aH1, aRow, sl0, sl1);                                              \
    if (GS_) STAGE_A((T_) + 2, 1);                                             \
    SCHEDB(); VM_P2; BARRIER(); SCHEDB();                                      \
    __builtin_amdgcn_s_setprio(1); mfma32(acc, 4, af, BCUR);                   \
    __builtin_amdgcn_s_setprio(0); SCHEDB();                                   \
  } while (0)

  for (int it = 0; it < (NT - 2) / 2; ++it) {
    const int T = it * 2;
    TILE(T,     bX, bY, true, true, VMCNT(14));
    TILE(T + 1, bY, bX, true, true, VMCNT(14));
  }
  // tail: tiles NT-2 (bX), NT-1 (bY); stages beyond NT stop.
  TILE(NT - 2, bX, bY, true,  false, VMCNT(10));
  TILE(NT - 1, bY, bX, false, false, (void)0);

  // ---- epilogue ----
  int colBase = tn * 256 + wc * 64 + ln15;
  int rowBase = tm * 256 + wr * 128 + l16 * 4;
#pragma unroll
  for (int n = 0; n < 4; ++n) {
    float bv = bias[colBase + n * 16];
#pragma unroll
    for (int m = 0; m < 8; ++m) {
#pragma unroll
      for (int j = 0; j < 4; ++j) {
        C[(size_t)(rowBase + m * 16 + j) * N + colBase + n * 16] = acc[m][n][j] + bv;
      }
    }
  }
#undef TILE
#undef STAGE_A
#undef GLOAD
}

extern "C" void kernel_launch(void* const* d_in, const int* in_sizes, int n_in,
                              void* d_out, int out_size, void* d_ws, size_t ws_size,
                              hipStream_t stream) {
  const float* A = (const float*)d_in[0];
  const int* Bq = (const int*)d_in[1];
  const int* meta = (const int*)d_in[2];
  const float* s = (const float*)d_in[3];
  const float* bias = (const float*)d_in[4];
  float* C = (float*)d_out;

  const int N = in_sizes[4];
  const int K = (int)(((long long)in_sizes[1] * 16) / N);
  const int M = (int)((long long)in_sizes[0] / K);
  const int sRows = (int)((long long)in_sizes[3] / N);       // K/GS
  const int chunksPerGroup = (K / sRows) / 32;               // GS/32

  h16* Ah = (h16*)d_ws;                       // M*K f16 = 64 MiB
  h16* Wt = Ah + (size_t)M * K;               // N*K f16 = 32 MiB (W^T, K-major)

  cvtA_kernel<<<2048, 256, 0, stream>>>(A, Ah, (M * K) / 8);

  dim3 dgrid(N / 256, K / 32);
  dequant_kernel<<<dgrid, 256, 0, stream>>>(Bq, meta, s, Wt, K, N, chunksPerGroup);

  int grid = (M / 256) * (N / 256);
  gemm_kernel<<<grid, 512, 0, stream>>>(Ah, Wt, bias, C, M, N, K);
}

// Round 9
// 320.508 us; speedup vs baseline: 1.4625x; 1.4625x over previous
//
#include <hip/hip_runtime.h>

typedef _Float16 h16;
typedef __attribute__((ext_vector_type(8))) _Float16 h16x8;
typedef __attribute__((ext_vector_type(4))) float f32x4;
typedef __attribute__((ext_vector_type(16))) float f32x16;
typedef unsigned int u32;

#define BARRIER() __builtin_amdgcn_s_barrier()
#define SCHEDB()  __builtin_amdgcn_sched_barrier(0)

// ---------------- Kernel 1: A fp32 -> fp16 ----------------
__global__ __launch_bounds__(256) void cvtA_kernel(const float* __restrict__ A,
                                                   h16* __restrict__ Ah, int total8) {
  int stride = gridDim.x * blockDim.x;
  for (int i = blockIdx.x * blockDim.x + threadIdx.x; i < total8; i += stride) {
    const f32x4* p = (const f32x4*)(A + (size_t)i * 8);
    f32x4 v0 = p[0], v1 = p[1];
    h16x8 o;
    o[0] = (h16)v0[0]; o[1] = (h16)v0[1]; o[2] = (h16)v0[2]; o[3] = (h16)v0[3];
    o[4] = (h16)v1[0]; o[5] = (h16)v1[1]; o[6] = (h16)v1[2]; o[7] = (h16)v1[3];
    *(h16x8*)(Ah + (size_t)i * 8) = o;
  }
}

// ---------------- Kernel 2: dequant 2:4 int4 -> Wt [N][K] fp16 ----------------
__global__ __launch_bounds__(256) void dequant_kernel(const int* __restrict__ Bq,
    const int* __restrict__ meta, const float* __restrict__ s,
    h16* __restrict__ Wt, int K, int N, int chunksPerGroup) {
  int n = blockIdx.x * 256 + threadIdx.x;
  int chunk = blockIdx.y;
  u32 w0 = (u32)Bq[(size_t)(chunk * 2) * N + n];
  u32 w1 = (u32)Bq[(size_t)(chunk * 2 + 1) * N + n];
  float sc = s[(size_t)(chunk / chunksPerGroup) * N + n];
  h16 out[32];
#pragma unroll
  for (int gi = 0; gi < 8; ++gi) {
    int g = chunk * 8 + gi;
    int mm = meta[(size_t)g * N + n];
    u32 w = (gi < 4) ? w0 : w1;
    int j0 = (2 * gi) & 7;
    float d0 = (float)((int)((w >> (4 * j0)) & 0xFu) - 8) * sc;
    float d1 = (float)((int)((w >> (4 * j0 + 4)) & 0xFu) - 8) * sc;
    u32 enc = (0xED9C84u >> (4 * mm)) & 0xFu;
    int p0 = (int)(enc & 3u), p1 = (int)(enc >> 2);
#pragma unroll
    for (int p = 0; p < 4; ++p) {
      float v = (p == p0) ? d0 : ((p == p1) ? d1 : 0.0f);
      out[gi * 4 + p] = (h16)v;
    }
  }
  h16* dst = Wt + (size_t)n * K + chunk * 32;
  *(h16x8*)(dst + 0)  = *(h16x8*)(out + 0);
  *(h16x8*)(dst + 8)  = *(h16x8*)(out + 8);
  *(h16x8*)(dst + 16) = *(h16x8*)(out + 16);
  *(h16x8*)(dst + 24) = *(h16x8*)(out + 24);
}

// ---------------- Kernel 3: GEMM, R5 schedule + 32x32x16 MFMA ----------------
// 256x256 tile, K-tiles of 64 (4 k-steps of 16), 512 threads (8 waves 2Mx4N),
// per-wave 128x64 out = 4 m-tiles x 2 n-tiles of 32x32, acc 8 x f32x16.
// LDS: A[2buf][2half][128 rows x 64] + B same = 128 KiB (layout identical R5).
// Phases per K-tile (R5-verified calendar, unchanged):
//   P1: rd B-h0(4)+A-h0(8), stage (T+1).A-h1 ; MFMA Q(mh0,nh0)
//   P2: rd B-h1(4),         stage (T+2).A-h0 ; MFMA Q(mh0,nh1)
//   P3: rd A-h1(8),         stage (T+2).B-h0 ; MFMA Q(mh1,nh1)
//   P4: (no reads),         stage (T+2).B-h1 ; MFMA Q(mh1,nh0); vmcnt(6)
__global__ __launch_bounds__(512, 2) void gemm_kernel(const h16* __restrict__ A,
    const h16* __restrict__ Wt, const float* __restrict__ bias,
    float* __restrict__ C, int M, int N, int K) {
  __shared__ alignas(16) h16 As[2 * 2 * 8192];
  __shared__ alignas(16) h16 Bs[2 * 2 * 8192];

  const int nTilesN = N >> 8;
  const int nwg = gridDim.x;
  int bid = blockIdx.x;
  int wg = (bid & 7) * (nwg >> 3) + (bid >> 3);   // XCD swizzle (nwg%8==0)
  int tm = wg / nTilesN, tn = wg - tm * nTilesN;

  const int tid = threadIdx.x;
  const int lane = tid & 63, w = tid >> 6;
  const int wr = w >> 2, wc = w & 3;

  // ---- staging addressing (pre-swizzled global source, linear LDS dest) ----
  const int i0 = tid >> 3;                         // row within 64-row chunk
  const int sigma = (tid & 7) ^ ((tid >> 3) & 7);  // source 16B-slot
  const h16* gA_t = A + ((size_t)(tm * 256) + i0) * K + sigma * 8;
  const int rB0 = ((i0 >> 5) << 6) + (i0 & 31);    // B stripe-compact row
  const h16* gB_t = Wt + ((size_t)(tn * 256) + rB0) * K + sigma * 8;
  const int tid8 = tid * 8;
  const size_t rowK128 = (size_t)128 * K;

#define GLOAD(SRC, DST) __builtin_amdgcn_global_load_lds(                      \
    (const __attribute__((address_space(1))) void*)(SRC),                      \
    (__attribute__((address_space(3))) void*)(DST), 16, 0, 0)

#define STAGE_A(T_, mh_) do {                                                  \
    const h16* s_ = gA_t + (size_t)((mh_) * 64) * K + (T_) * 64;               \
    h16* d_ = As + ((((T_) & 1) * 2 + (mh_)) * 8192) + tid8;                   \
    GLOAD(s_, d_); GLOAD(s_ + rowK128, d_ + 4096); } while (0)

#define STAGE_B(T_, nh_) do {                                                  \
    const h16* s_ = gB_t + (size_t)((nh_) * 32) * K + (T_) * 64;               \
    h16* d_ = Bs + ((((T_) & 1) * 2 + (nh_)) * 8192) + tid8;                   \
    GLOAD(s_, d_); GLOAD(s_ + rowK128, d_ + 4096); } while (0)

  // ---- fragment read offsets (h16), swizzled slot = (kst*2+l5)^l7 ----
  const int l31 = lane & 31, l5 = lane >> 5, l7 = lane & 7;
  const int aR = (wr * 64 + l31) * 64;     // A half-local row (wr*64 + mtl*32+l31)
  const int bR = (wc * 32 + l31) * 64;     // B half-local row
  int sl[4];
#pragma unroll
  for (int kst = 0; kst < 4; ++kst) sl[kst] = ((kst * 2 + l5) ^ l7) * 8;

  f32x16 acc[4][2] = {};                   // [m-tile][n-tile] of 32x32
  const int NT = K >> 6;

  // prologue: 7 half-tiles (t0 complete + t1.Ah0/Bh0/Bh1); retire t0.
  STAGE_A(0, 0); STAGE_B(0, 0); STAGE_B(0, 1); STAGE_A(0, 1);
  STAGE_A(1, 0); STAGE_B(1, 0); STAGE_B(1, 1);
  asm volatile("s_waitcnt vmcnt(6)" ::: "memory");
  SCHEDB();
  BARRIER();

  for (int T = 0; T < NT; ++T) {
    const int buf = T & 1;
    const h16* a0 = As + (buf * 2 + 0) * 8192;
    const h16* a1 = As + (buf * 2 + 1) * 8192;
    const h16* b0 = Bs + (buf * 2 + 0) * 8192;
    const h16* b1 = Bs + (buf * 2 + 1) * 8192;
    h16x8 af[2][4], bf0[4], bf1[4];

    // ================= P1: Q(mh0, nh0) =================
#pragma unroll
    for (int k = 0; k < 4; ++k) bf0[k] = *(const h16x8*)(b0 + bR + sl[k]);
#pragma unroll
    for (int mtl = 0; mtl < 2; ++mtl)
#pragma unroll
      for (int k = 0; k < 4; ++k)
        af[mtl][k] = *(const h16x8*)(a0 + aR + mtl * 2048 + sl[k]);
    if (T + 1 < NT) STAGE_A(T + 1, 1);
    asm volatile("s_waitcnt lgkmcnt(8)" ::: "memory");
    SCHEDB();
    BARRIER();
    asm volatile("s_waitcnt lgkmcnt(0)" ::: "memory");
    SCHEDB();
    __builtin_amdgcn_s_setprio(1);
#pragma unroll
    for (int k = 0; k < 4; ++k)
#pragma unroll
      for (int mtl = 0; mtl < 2; ++mtl)
        acc[mtl][0] = __builtin_amdgcn_mfma_f32_32x32x16_f16(af[mtl][k], bf0[k], acc[mtl][0], 0, 0, 0);
    __builtin_amdgcn_s_setprio(0);
    SCHEDB();
    BARRIER();

    // ================= P2: Q(mh0, nh1) =================
#pragma unroll
    for (int k = 0; k < 4; ++k) bf1[k] = *(const h16x8*)(b1 + bR + sl[k]);
    if (T + 2 < NT) STAGE_A(T + 2, 0);
    SCHEDB();
    BARRIER();
    asm volatile("s_waitcnt lgkmcnt(0)" ::: "memory");
    SCHEDB();
    __builtin_amdgcn_s_setprio(1);
#pragma unroll
    for (int k = 0; k < 4; ++k)
#pragma unroll
      for (int mtl = 0; mtl < 2; ++mtl)
        acc[mtl][1] = __builtin_amdgcn_mfma_f32_32x32x16_f16(af[mtl][k], bf1[k], acc[mtl][1], 0, 0, 0);
    __builtin_amdgcn_s_setprio(0);
    SCHEDB();
    BARRIER();

    // ================= P3: Q(mh1, nh1) =================
#pragma unroll
    for (int mtl = 0; mtl < 2; ++mtl)
#pragma unroll
      for (int k = 0; k < 4; ++k)
        af[mtl][k] = *(const h16x8*)(a1 + aR + mtl * 2048 + sl[k]);
    if (T + 2 < NT) STAGE_B(T + 2, 0);
    SCHEDB();
    BARRIER();
    asm volatile("s_waitcnt lgkmcnt(0)" ::: "memory");
    SCHEDB();
    __builtin_amdgcn_s_setprio(1);
#pragma unroll
    for (int k = 0; k < 4; ++k)
#pragma unroll
      for (int mtl = 0; mtl < 2; ++mtl)
        acc[2 + mtl][1] = __builtin_amdgcn_mfma_f32_32x32x16_f16(af[mtl][k], bf1[k], acc[2 + mtl][1], 0, 0, 0);
    __builtin_amdgcn_s_setprio(0);
    SCHEDB();
    BARRIER();

    // ================= P4: Q(mh1, nh0) =================
    if (T + 2 < NT) STAGE_B(T + 2, 1);
    SCHEDB();
    BARRIER();
    SCHEDB();
    __builtin_amdgcn_s_setprio(1);
#pragma unroll
    for (int k = 0; k < 4; ++k)
#pragma unroll
      for (int mtl = 0; mtl < 2; ++mtl)
        acc[2 + mtl][0] = __builtin_amdgcn_mfma_f32_32x32x16_f16(af[mtl][k], bf0[k], acc[2 + mtl][0], 0, 0, 0);
    __builtin_amdgcn_s_setprio(0);
    if (T < NT - 2) {
      asm volatile("s_waitcnt vmcnt(6)" ::: "memory");
    } else if (T == NT - 2) {
      asm volatile("s_waitcnt vmcnt(0)" ::: "memory");
    }
    SCHEDB();
    BARRIER();
  }

  // ---- epilogue: D col=lane&31 (B side), row=(reg&3)+8*(reg>>2)+4*(lane>>5) --
  int colB = tn * 256 + wc * 64 + l31;
  int rowB = tm * 256 + wr * 128 + l5 * 4;
#pragma unroll
  for (int nt = 0; nt < 2; ++nt) {
    float bv = bias[colB + nt * 32];
#pragma unroll
    for (int mt = 0; mt < 4; ++mt) {
#pragma unroll
      for (int q = 0; q < 4; ++q) {
#pragma unroll
        for (int j = 0; j < 4; ++j) {
          C[(size_t)(rowB + mt * 32 + q * 8 + j) * N + colB + nt * 32] =
              acc[mt][nt][q * 4 + j] + bv;
        }
      }
    }
  }
#undef STAGE_A
#undef STAGE_B
#undef GLOAD
}

extern "C" void kernel_launch(void* const* d_in, const int* in_sizes, int n_in,
                              void* d_out, int out_size, void* d_ws, size_t ws_size,
                              hipStream_t stream) {
  const float* A = (const float*)d_in[0];
  const int* Bq = (const int*)d_in[1];
  const int* meta = (const int*)d_in[2];
  const float* s = (const float*)d_in[3];
  const float* bias = (const float*)d_in[4];
  float* C = (float*)d_out;

  const int N = in_sizes[4];
  const int K = (int)(((long long)in_sizes[1] * 16) / N);
  const int M = (int)((long long)in_sizes[0] / K);
  const int sRows = (int)((long long)in_sizes[3] / N);       // K/GS
  const int chunksPerGroup = (K / sRows) / 32;               // GS/32

  h16* Ah = (h16*)d_ws;                       // M*K f16 = 64 MiB
  h16* Wt = Ah + (size_t)M * K;               // N*K f16 = 32 MiB (W^T, K-major)

  cvtA_kernel<<<2048, 256, 0, stream>>>(A, Ah, (M * K) / 8);

  dim3 dgrid(N / 256, K / 32);
  dequant_kernel<<<dgrid, 256, 0, stream>>>(Bq, meta, s, Wt, K, N, chunksPerGroup);

  int grid = (M / 256) * (N / 256);
  gemm_kernel<<<grid, 512, 0, stream>>>(Ah, Wt, bias, C, M, N, K);
}